// Round 3
// baseline (434.102 us; speedup 1.0000x reference)
//
#include <hip/hip_runtime.h>
#include <stdint.h>

#define TD 4096
#define DD 1024
#define SENT 9999.0f

typedef __attribute__((ext_vector_type(4))) float f32x4;
typedef __attribute__((ext_vector_type(8))) short short8;
typedef __attribute__((ext_vector_type(4))) unsigned short ushort4v;

__device__ __forceinline__ unsigned short f2bf(float f) {
  union { float f; unsigned int u; } v; v.f = f;
  unsigned int u = v.u;
  return (unsigned short)((u + 0x7FFFu + ((u >> 16) & 1u)) >> 16);
}

// async global->LDS 16B copy; LDS dest is wave-uniform base + lane*16
__device__ __forceinline__ void gld_lds16(const void* g, void* l) {
  __builtin_amdgcn_global_load_lds(
      (const __attribute__((address_space(1))) unsigned int*)(size_t)g,
      (__attribute__((address_space(3))) unsigned int*)(unsigned int)(size_t)l,
      16, 0, 0);
}

__global__ __launch_bounds__(256) void k_init(unsigned long long* row_min, float* out) {
  int i = blockIdx.x * 256 + threadIdx.x;
  if (i < TD) row_min[i] = ~0ull;
  if (i == 0) out[0] = 0.0f;
}

__global__ __launch_bounds__(256) void k_prep(
    const float* __restrict__ X, const float* __restrict__ H,
    const float* __restrict__ C, const float* __restrict__ M,
    unsigned short* __restrict__ Mbh, unsigned short* __restrict__ MHh,
    unsigned short* __restrict__ MH2h, int* __restrict__ am,
    float* __restrict__ out)
{
  const int row = blockIdx.x;
  const int tid = threadIdx.x;
  const size_t base = (size_t)row * DD;
  f32x4 x = ((const f32x4*)(X + base))[tid];
  f32x4 h = ((const f32x4*)(H + base))[tid];
  f32x4 c = ((const f32x4*)(C + base))[tid];
  f32x4 m = ((const f32x4*)(M + base))[tid];
  float mse = 0.0f;
  int cand = 0x7FFFFFFF;
  ushort4v mb, mh, mh2;
#pragma unroll
  for (int e = 0; e < 4; ++e) {
    float mv = m[e], hv = h[e];
    float mbv = (mv > 0.0f) ? 1.0f : 0.0f;
    float mhv = mbv * hv;
    float mh2v = mhv * hv;
    mb[e] = f2bf(mbv);
    mh[e] = f2bf(mhv);
    mh2[e] = f2bf(mh2v);
    float t = (x[e] - (hv - c[e])) * mv;
    mse += t * t;
    int d = tid * 4 + e;
    if (mv == 0.0f && d < cand) cand = d;
  }
  *(ushort4v*)(Mbh + base + tid * 4) = mb;
  *(ushort4v*)(MHh + base + tid * 4) = mh;
  *(ushort4v*)(MH2h + base + tid * 4) = mh2;
#pragma unroll
  for (int o = 32; o > 0; o >>= 1) {
    mse += __shfl_down(mse, o);
    int oc = __shfl_down(cand, o);
    cand = (oc < cand) ? oc : cand;
  }
  __shared__ float rs[4];
  __shared__ int ri[4];
  if ((tid & 63) == 0) { rs[tid >> 6] = mse; ri[tid >> 6] = cand; }
  __syncthreads();
  if (tid == 0) {
    float s = rs[0] + rs[1] + rs[2] + rs[3];
    int cm = ri[0];
    cm = (ri[1] < cm) ? ri[1] : cm;
    cm = (ri[2] < cm) ? ri[2] : cm;
    cm = (ri[3] < cm) ? ri[3] : cm;
    atomicAdd(out, s);
    am[row] = (cm == 0x7FFFFFFF) ? 0 : cm;
  }
}

// 64x64 tile pairwise masked-variance + fused per-row packed argmin.
// LDS: 6 tiles (A:Mb,MH,MH2 / B:Mb,MH,MH2) of [64][64] bf16 = 48 KB.
// Swizzle: LDS[row][slot] holds global chunk (slot ^ (row&7)) (16B chunks),
// achieved by pre-swizzling the per-lane GLOBAL source of global_load_lds.
__global__ __launch_bounds__(256, 2) void k_pairvar(
    const unsigned short* __restrict__ Mb, const unsigned short* __restrict__ MH,
    const unsigned short* __restrict__ MH2, const int* __restrict__ am,
    unsigned long long* __restrict__ row_min)
{
  __shared__ unsigned short lds[6 * 64 * 64];
  const int tid = threadIdx.x;
  const int lane = tid & 63;
  const int w = tid >> 6;      // wave 0..3
  const int wr = w >> 1, wc = w & 1;
  const int i0 = blockIdx.y * 64, j0 = blockIdx.x * 64;

  const unsigned short* mats[3] = { Mb, MH, MH2 };
  const int l_row = lane >> 3;           // row within 8-row staging block
  const int l_ch = lane & 7;             // dest chunk slot
  const int sw_ch = l_ch ^ l_row;        // swizzled source chunk

  const unsigned short* gsrc[12];
  unsigned int ldsoff[12];
#pragma unroll
  for (int s = 0; s < 12; ++s) {
    int t = w * 12 + s;                  // 0..47
    int tile = t >> 3;                   // 0..5
    int rowblk = t & 7;                  // 8-row block within tile
    int mat = (tile < 3) ? tile : (tile - 3);
    int rbase = (tile < 3) ? i0 : j0;
    int grow = rbase + rowblk * 8 + l_row;
    gsrc[s] = mats[mat] + (size_t)grow * DD + sw_ch * 8;
    ldsoff[s] = (unsigned int)((tile * 4096 + rowblk * 512) * 2); // bytes
  }

  f32x4 acc[6][2][2] = {};

  for (int kt = 0; kt < DD / 64; ++kt) {
#pragma unroll
    for (int s = 0; s < 12; ++s)
      gld_lds16(gsrc[s] + kt * 64, (char*)lds + ldsoff[s]);
    __syncthreads();
#pragma unroll
    for (int kc = 0; kc < 2; ++kc) {
      short8 aF[3][2], bF[3][2];
      const int ksub = kc * 4 + (lane >> 4);  // 16B chunk index along K
#pragma unroll
      for (int m = 0; m < 2; ++m) {
        const int r = wr * 32 + m * 16 + (lane & 15);
        const int sl = ksub ^ (r & 7);
#pragma unroll
        for (int mat = 0; mat < 3; ++mat)
          aF[mat][m] = *(const short8*)&lds[mat * 4096 + r * 64 + sl * 8];
      }
#pragma unroll
      for (int n = 0; n < 2; ++n) {
        const int r = wc * 32 + n * 16 + (lane & 15);
        const int sl = ksub ^ (r & 7);
#pragma unroll
        for (int mat = 0; mat < 3; ++mat)
          bF[mat][n] = *(const short8*)&lds[(3 + mat) * 4096 + r * 64 + sl * 8];
      }
#pragma unroll
      for (int m = 0; m < 2; ++m)
#pragma unroll
        for (int n = 0; n < 2; ++n) {
          acc[0][m][n] = __builtin_amdgcn_mfma_f32_16x16x32_bf16(aF[0][m], bF[0][n], acc[0][m][n], 0, 0, 0); // n
          acc[1][m][n] = __builtin_amdgcn_mfma_f32_16x16x32_bf16(aF[1][m], bF[0][n], acc[1][m][n], 0, 0, 0); // <MH_i,Mb_j>
          acc[2][m][n] = __builtin_amdgcn_mfma_f32_16x16x32_bf16(aF[0][m], bF[1][n], acc[2][m][n], 0, 0, 0); // <Mb_i,MH_j>
          acc[3][m][n] = __builtin_amdgcn_mfma_f32_16x16x32_bf16(aF[2][m], bF[0][n], acc[3][m][n], 0, 0, 0); // <MH2_i,Mb_j>
          acc[4][m][n] = __builtin_amdgcn_mfma_f32_16x16x32_bf16(aF[0][m], bF[2][n], acc[4][m][n], 0, 0, 0); // <Mb_i,MH2_j>
          acc[5][m][n] = __builtin_amdgcn_mfma_f32_16x16x32_bf16(aF[1][m], bF[1][n], acc[5][m][n], 0, 0, 0); // <MH_i,MH_j>
        }
    }
    __syncthreads();
  }

  // epilogue: var + validity + packed per-row argmin
  const int cl = lane & 15;
  int amj[2];
#pragma unroll
  for (int n = 0; n < 2; ++n) amj[n] = am[j0 + wc * 32 + n * 16 + cl];

#pragma unroll
  for (int m = 0; m < 2; ++m) {
#pragma unroll
    for (int q = 0; q < 4; ++q) {
      const int gi = i0 + wr * 32 + m * 16 + (lane >> 4) * 4 + q;
      const int ami = am[gi];
      unsigned long long best = ~0ull;
#pragma unroll
      for (int n = 0; n < 2; ++n) {
        const int gj = j0 + wc * 32 + n * 16 + cl;
        const float nv = acc[0][m][n][q];
        const float bb = acc[1][m][n][q];
        const float bt = acc[2][m][n][q];
        const float cc = acc[3][m][n][q];
        const float ct = acc[4][m][n][q];
        const float dd = acc[5][m][n][q];
        const float s1 = bb - bt;
        const float s2 = cc - 2.0f * dd + ct;
        const float nsafe = fmaxf(nv, 2.0f);
        const float var = (s2 - s1 * s1 / nsafe) / (nsafe - 1.0f);
        const bool valid = (gi != gj) && (ami != amj[n]) && (nv > 1.5f);
        const float score = valid ? var : SENT;
        unsigned int ub = __float_as_uint(score);
        unsigned int key = (ub & 0x80000000u) ? ~ub : (ub | 0x80000000u);
        unsigned long long pk = ((unsigned long long)key << 32) | (unsigned int)gj;
        if (pk < best) best = pk;
      }
#pragma unroll
      for (int o = 1; o < 16; o <<= 1) {
        unsigned long long other = __shfl_xor(best, o);
        if (other < best) best = other;
      }
      if (cl == 0) atomicMin(&row_min[gi], best);
    }
  }
}

__global__ __launch_bounds__(256) void k_final(
    const float* __restrict__ H, const unsigned long long* __restrict__ row_min,
    float* __restrict__ out)
{
  const int i = blockIdx.x;
  const int tid = threadIdx.x;
  const int j = (int)(unsigned int)(row_min[i] & 0xFFFFFFFFull);
  f32x4 a = ((const f32x4*)(H + (size_t)i * DD))[tid];
  f32x4 b = ((const f32x4*)(H + (size_t)j * DD))[tid];
  float s = 0.0f;
#pragma unroll
  for (int e = 0; e < 4; ++e) {
    float d = a[e] - b[e];
    s += d * d;
  }
#pragma unroll
  for (int o = 32; o > 0; o >>= 1) s += __shfl_down(s, o);
  __shared__ float rs[4];
  if ((tid & 63) == 0) rs[tid >> 6] = s;
  __syncthreads();
  if (tid == 0) {
    float tot = rs[0] + rs[1] + rs[2] + rs[3];
    atomicAdd(out, 10.0f * sqrtf(tot));
  }
}

extern "C" void kernel_launch(void* const* d_in, const int* in_sizes, int n_in,
                              void* d_out, int out_size, void* d_ws, size_t ws_size,
                              hipStream_t stream) {
  const float* X = (const float*)d_in[0];
  const float* H = (const float*)d_in[1];
  const float* C = (const float*)d_in[2];
  const float* M = (const float*)d_in[3];
  float* out = (float*)d_out;

  const size_t SZ = (size_t)TD * DD * sizeof(unsigned short); // 8 MB per bf16 matrix
  char* ws = (char*)d_ws;
  unsigned short* Mbh = (unsigned short*)(ws);
  unsigned short* MHh = (unsigned short*)(ws + SZ);
  unsigned short* MH2h = (unsigned short*)(ws + 2 * SZ);
  int* am = (int*)(ws + 3 * SZ);
  unsigned long long* row_min = (unsigned long long*)(ws + 3 * SZ + TD * sizeof(int));

  k_init<<<dim3((TD + 255) / 256), dim3(256), 0, stream>>>(row_min, out);
  k_prep<<<dim3(TD), dim3(256), 0, stream>>>(X, H, C, M, Mbh, MHh, MH2h, am, out);
  k_pairvar<<<dim3(TD / 64, TD / 64), dim3(256), 0, stream>>>(Mbh, MHh, MH2h, am, row_min);
  k_final<<<dim3(TD), dim3(256), 0, stream>>>(H, row_min, out);
}

// Round 7
// 321.588 us; speedup vs baseline: 1.3499x; 1.3499x over previous
//
#include <hip/hip_runtime.h>
#include <stdint.h>

#define TD 4096
#define DD 1024
#define SENT 9999.0f

typedef __attribute__((ext_vector_type(4))) float f32x4;
typedef __attribute__((ext_vector_type(8))) short short8;
typedef __attribute__((ext_vector_type(4))) unsigned short ushort4v;

__device__ __forceinline__ unsigned short f2bf(float f) {
  union { float f; unsigned int u; } v; v.f = f;
  unsigned int u = v.u;
  return (unsigned short)((u + 0x7FFFu + ((u >> 16) & 1u)) >> 16);
}

// async global->LDS 16B copy; LDS dest is wave-uniform base + lane*16
__device__ __forceinline__ void gld_lds16(const void* g, void* l) {
  __builtin_amdgcn_global_load_lds(
      (const __attribute__((address_space(1))) unsigned int*)(size_t)g,
      (__attribute__((address_space(3))) unsigned int*)(unsigned int)(size_t)l,
      16, 0, 0);
}

__global__ __launch_bounds__(256) void k_init(unsigned long long* row_min, float* out) {
  int i = blockIdx.x * 256 + threadIdx.x;
  if (i < TD) row_min[i] = ~0ull;
  if (i == 0) out[0] = 0.0f;
}

__global__ __launch_bounds__(256) void k_prep(
    const float* __restrict__ X, const float* __restrict__ H,
    const float* __restrict__ C, const float* __restrict__ M,
    unsigned short* __restrict__ Mbh, unsigned short* __restrict__ MHh,
    unsigned short* __restrict__ MH2h, int* __restrict__ am,
    float* __restrict__ out)
{
  const int row = blockIdx.x;
  const int tid = threadIdx.x;
  const size_t base = (size_t)row * DD;
  f32x4 x = ((const f32x4*)(X + base))[tid];
  f32x4 h = ((const f32x4*)(H + base))[tid];
  f32x4 c = ((const f32x4*)(C + base))[tid];
  f32x4 m = ((const f32x4*)(M + base))[tid];
  float mse = 0.0f;
  int cand = 0x7FFFFFFF;
  ushort4v mb, mh, mh2;
#pragma unroll
  for (int e = 0; e < 4; ++e) {
    float mv = m[e], hv = h[e];
    float mbv = (mv > 0.0f) ? 1.0f : 0.0f;
    float mhv = mbv * hv;
    float mh2v = mhv * hv;
    mb[e] = f2bf(mbv);
    mh[e] = f2bf(mhv);
    mh2[e] = f2bf(mh2v);
    float t = (x[e] - (hv - c[e])) * mv;
    mse += t * t;
    int d = tid * 4 + e;
    if (mv == 0.0f && d < cand) cand = d;
  }
  *(ushort4v*)(Mbh + base + tid * 4) = mb;
  *(ushort4v*)(MHh + base + tid * 4) = mh;
  *(ushort4v*)(MH2h + base + tid * 4) = mh2;
#pragma unroll
  for (int o = 32; o > 0; o >>= 1) {
    mse += __shfl_down(mse, o);
    int oc = __shfl_down(cand, o);
    cand = (oc < cand) ? oc : cand;
  }
  __shared__ float rs[4];
  __shared__ int ri[4];
  if ((tid & 63) == 0) { rs[tid >> 6] = mse; ri[tid >> 6] = cand; }
  __syncthreads();
  if (tid == 0) {
    float s = rs[0] + rs[1] + rs[2] + rs[3];
    int cm = ri[0];
    cm = (ri[1] < cm) ? ri[1] : cm;
    cm = (ri[2] < cm) ? ri[2] : cm;
    cm = (ri[3] < cm) ? ri[3] : cm;
    atomicAdd(out, s);
    am[row] = (cm == 0x7FFFFFFF) ? 0 : cm;
  }
}

// Triangular 64x64 tile pairwise masked-variance + fused per-row packed argmin.
// score(i,j)==score(j,i) exactly (n,s2 symmetric; s1 antisym but only s1^2 used;
// we reuse the SAME fp32 var for both updates), so only 2080 lower-tri blocks run.
// LDS: 6 tiles (A:Mb,MH,MH2 / B:Mb,MH,MH2) of [64][64] bf16 = 48 KB -> 3 blocks/CU.
// Swizzle: LDS[row][slot] holds global chunk (slot ^ (row&7)) (16B chunks),
// achieved by pre-swizzling the per-lane GLOBAL source of global_load_lds.
__global__ __launch_bounds__(256, 3) void k_pairvar(
    const unsigned short* __restrict__ Mb, const unsigned short* __restrict__ MH,
    const unsigned short* __restrict__ MH2, const int* __restrict__ am,
    unsigned long long* __restrict__ row_min)
{
  __shared__ unsigned short lds[6 * 64 * 64];
  const int tid = threadIdx.x;
  const int lane = tid & 63;
  const int w = tid >> 6;      // wave 0..3
  const int wr = w >> 1, wc = w & 1;

  // decode linear block id -> lower-triangular (bi >= bj)
  const int kblk = blockIdx.x;
  int bi = (int)((sqrtf(8.0f * (float)kblk + 1.0f) - 1.0f) * 0.5f);
  while ((bi + 1) * (bi + 2) / 2 <= kblk) ++bi;
  while (bi * (bi + 1) / 2 > kblk) --bi;
  const int bj = kblk - bi * (bi + 1) / 2;
  const int i0 = bi * 64, j0 = bj * 64;

  const unsigned short* mats[3] = { Mb, MH, MH2 };
  const int l_row = lane >> 3;           // row within 8-row staging block
  const int l_ch = lane & 7;             // dest chunk slot
  const int sw_ch = l_ch ^ l_row;        // swizzled source chunk

  const unsigned short* gsrc[12];
  unsigned int ldsoff[12];
#pragma unroll
  for (int s = 0; s < 12; ++s) {
    int t = w * 12 + s;                  // 0..47
    int tile = t >> 3;                   // 0..5
    int rowblk = t & 7;                  // 8-row block within tile
    int mat = (tile < 3) ? tile : (tile - 3);
    int rbase = (tile < 3) ? i0 : j0;
    int grow = rbase + rowblk * 8 + l_row;
    gsrc[s] = mats[mat] + (size_t)grow * DD + sw_ch * 8;
    ldsoff[s] = (unsigned int)((tile * 4096 + rowblk * 512) * 2); // bytes
  }

  f32x4 acc[6][2][2] = {};

  for (int kt = 0; kt < DD / 64; ++kt) {
#pragma unroll
    for (int s = 0; s < 12; ++s)
      gld_lds16(gsrc[s] + kt * 64, (char*)lds + ldsoff[s]);
    __syncthreads();
#pragma unroll
    for (int kc = 0; kc < 2; ++kc) {
      short8 aF[3][2], bF[3][2];
      const int ksub = kc * 4 + (lane >> 4);  // 16B chunk index along K
#pragma unroll
      for (int m = 0; m < 2; ++m) {
        const int r = wr * 32 + m * 16 + (lane & 15);
        const int sl = ksub ^ (r & 7);
#pragma unroll
        for (int mat = 0; mat < 3; ++mat)
          aF[mat][m] = *(const short8*)&lds[mat * 4096 + r * 64 + sl * 8];
      }
#pragma unroll
      for (int n = 0; n < 2; ++n) {
        const int r = wc * 32 + n * 16 + (lane & 15);
        const int sl = ksub ^ (r & 7);
#pragma unroll
        for (int mat = 0; mat < 3; ++mat)
          bF[mat][n] = *(const short8*)&lds[(3 + mat) * 4096 + r * 64 + sl * 8];
      }
#pragma unroll
      for (int m = 0; m < 2; ++m)
#pragma unroll
        for (int n = 0; n < 2; ++n) {
          acc[0][m][n] = __builtin_amdgcn_mfma_f32_16x16x32_bf16(aF[0][m], bF[0][n], acc[0][m][n], 0, 0, 0); // n
          acc[1][m][n] = __builtin_amdgcn_mfma_f32_16x16x32_bf16(aF[1][m], bF[0][n], acc[1][m][n], 0, 0, 0); // <MH_i,Mb_j>
          acc[2][m][n] = __builtin_amdgcn_mfma_f32_16x16x32_bf16(aF[0][m], bF[1][n], acc[2][m][n], 0, 0, 0); // <Mb_i,MH_j>
          acc[3][m][n] = __builtin_amdgcn_mfma_f32_16x16x32_bf16(aF[2][m], bF[0][n], acc[3][m][n], 0, 0, 0); // <MH2_i,Mb_j>
          acc[4][m][n] = __builtin_amdgcn_mfma_f32_16x16x32_bf16(aF[0][m], bF[2][n], acc[4][m][n], 0, 0, 0); // <Mb_i,MH2_j>
          acc[5][m][n] = __builtin_amdgcn_mfma_f32_16x16x32_bf16(aF[1][m], bF[1][n], acc[5][m][n], 0, 0, 0); // <MH_i,MH_j>
        }
    }
    __syncthreads();
  }

  // epilogue: var + validity + packed argmin, scattered to BOTH row sets
  const int cl = lane & 15;
  const int lg = lane >> 4;
  int amj[2];
#pragma unroll
  for (int n = 0; n < 2; ++n) amj[n] = am[j0 + wc * 32 + n * 16 + cl];

  unsigned long long bestc[2] = { ~0ull, ~0ull };

#pragma unroll
  for (int m = 0; m < 2; ++m) {
#pragma unroll
    for (int q = 0; q < 4; ++q) {
      const int gi = i0 + wr * 32 + m * 16 + lg * 4 + q;
      const int ami = am[gi];
      unsigned long long best = ~0ull;
#pragma unroll
      for (int n = 0; n < 2; ++n) {
        const int gj = j0 + wc * 32 + n * 16 + cl;
        const float nv = acc[0][m][n][q];
        const float bb = acc[1][m][n][q];
        const float bt = acc[2][m][n][q];
        const float cc = acc[3][m][n][q];
        const float ct = acc[4][m][n][q];
        const float dd = acc[5][m][n][q];
        const float s1 = bb - bt;
        const float s2 = cc - 2.0f * dd + ct;
        const float nsafe = fmaxf(nv, 2.0f);
        const float var = (s2 - s1 * s1 / nsafe) / (nsafe - 1.0f);
        const bool valid = (gi != gj) && (ami != amj[n]) && (nv > 1.5f);
        const float score = valid ? var : SENT;
        unsigned int ub = __float_as_uint(score);
        unsigned int key = (ub & 0x80000000u) ? ~ub : (ub | 0x80000000u);
        unsigned long long pkr = ((unsigned long long)key << 32) | (unsigned int)gj;
        if (pkr < best) best = pkr;
        unsigned long long pkc = ((unsigned long long)key << 32) | (unsigned int)gi;
        if (pkc < bestc[n]) bestc[n] = pkc;
      }
#pragma unroll
      for (int o = 1; o < 16; o <<= 1) {
        unsigned long long other = __shfl_xor(best, o);
        if (other < best) best = other;
      }
      if (cl == 0) atomicMin(&row_min[gi], best);
    }
  }

  if (bi != bj) {
#pragma unroll
    for (int n = 0; n < 2; ++n) {
      unsigned long long b = bestc[n];
      unsigned long long o16 = __shfl_xor(b, 16);
      b = (o16 < b) ? o16 : b;
      unsigned long long o32 = __shfl_xor(b, 32);
      b = (o32 < b) ? o32 : b;
      if (lg == 0) atomicMin(&row_min[j0 + wc * 32 + n * 16 + cl], b);
    }
  }
}

__global__ __launch_bounds__(256) void k_final(
    const float* __restrict__ H, const unsigned long long* __restrict__ row_min,
    float* __restrict__ out)
{
  const int i = blockIdx.x;
  const int tid = threadIdx.x;
  const int j = (int)(unsigned int)(row_min[i] & 0xFFFFFFFFull);
  f32x4 a = ((const f32x4*)(H + (size_t)i * DD))[tid];
  f32x4 b = ((const f32x4*)(H + (size_t)j * DD))[tid];
  float s = 0.0f;
#pragma unroll
  for (int e = 0; e < 4; ++e) {
    float d = a[e] - b[e];
    s += d * d;
  }
#pragma unroll
  for (int o = 32; o > 0; o >>= 1) s += __shfl_down(s, o);
  __shared__ float rs[4];
  if ((tid & 63) == 0) rs[tid >> 6] = s;
  __syncthreads();
  if (tid == 0) {
    float tot = rs[0] + rs[1] + rs[2] + rs[3];
    atomicAdd(out, 10.0f * sqrtf(tot));
  }
}

extern "C" void kernel_launch(void* const* d_in, const int* in_sizes, int n_in,
                              void* d_out, int out_size, void* d_ws, size_t ws_size,
                              hipStream_t stream) {
  const float* X = (const float*)d_in[0];
  const float* H = (const float*)d_in[1];
  const float* C = (const float*)d_in[2];
  const float* M = (const float*)d_in[3];
  float* out = (float*)d_out;

  const size_t SZ = (size_t)TD * DD * sizeof(unsigned short); // 8 MB per bf16 matrix
  char* ws = (char*)d_ws;
  unsigned short* Mbh = (unsigned short*)(ws);
  unsigned short* MHh = (unsigned short*)(ws + SZ);
  unsigned short* MH2h = (unsigned short*)(ws + 2 * SZ);
  int* am = (int*)(ws + 3 * SZ);
  unsigned long long* row_min = (unsigned long long*)(ws + 3 * SZ + TD * sizeof(int));

  const int NT = TD / 64;                 // 64 tiles per side
  const int NBLK = NT * (NT + 1) / 2;     // 2080 triangular blocks

  k_init<<<dim3((TD + 255) / 256), dim3(256), 0, stream>>>(row_min, out);
  k_prep<<<dim3(TD), dim3(256), 0, stream>>>(X, H, C, M, Mbh, MHh, MH2h, am, out);
  k_pairvar<<<dim3(NBLK), dim3(256), 0, stream>>>(Mbh, MHh, MH2h, am, row_min);
  k_final<<<dim3(TD), dim3(256), 0, stream>>>(H, row_min, out);
}